// Round 6
// baseline (266.933 us; speedup 1.0000x reference)
//
#include <hip/hip_runtime.h>

// Problem constants
#define NQ     16384       // 4*16*16*16 query vectors
#define EDIM   256
#define NE     8192
#define LHW    4096        // 16*16*16
#define BETA   0.25f

// ws layout (bytes) — K=256 bf16-hi packing.
#define WS_WSQ    0            // f32[NE]             32768
#define WS_CNT    32768        // u32[NE]             32768
#define WS_LOSS   65536        // f32 (+pad)          256
#define WS_IDX    65792        // u32[NQ]             65536
#define WS_BEST   131328       // u64[NQ] (fallback)  131072
#define WS_APACK  2359552      // ushort[NQ*256]      8388608
#define WS_BPACK  10748160     // ushort[NE*256]      4194304
#define WS_NEED   14942464

typedef __attribute__((ext_vector_type(8))) short bf16x8;
typedef __attribute__((ext_vector_type(4))) float f32x4;

__device__ __forceinline__ unsigned f32_sortable(float f) {
    unsigned b = __float_as_uint(f);
    return b ^ ((unsigned)((int)b >> 31) | 0x80000000u);   // 3 VALU ops
}
__device__ __forceinline__ unsigned short bf16_rn(float f) {
    unsigned u = __float_as_uint(f);
    return (unsigned short)((u + 0x7FFFu + ((u >> 16) & 1u)) >> 16);
}

// K1a (MFMA path): wsq + pack_w (bf16-hi only) fused; zeroes counts/loss.
__global__ __launch_bounds__(256) void wsq_pack_w(const float* __restrict__ w,
                                                  float* __restrict__ wsq,
                                                  unsigned* __restrict__ Bp32,
                                                  unsigned* __restrict__ counts,
                                                  float* __restrict__ loss) {
    int wave = threadIdx.x >> 6, lane = threadIdx.x & 63;
    int row = blockIdx.x * 4 + wave;
    if (blockIdx.x < 32) {
        counts[blockIdx.x * 256 + threadIdx.x] = 0u;
        if (blockIdx.x == 0 && threadIdx.x == 0) loss[0] = 0.f;
    }
    float4 v = *(const float4*)(w + (size_t)row * EDIM + lane * 4);
    double s = (double)v.x * v.x + (double)v.y * v.y +
               (double)v.z * v.z + (double)v.w * v.w;
    unsigned p0 = (unsigned)bf16_rn(v.x) | ((unsigned)bf16_rn(v.y) << 16);
    unsigned p1 = (unsigned)bf16_rn(v.z) | ((unsigned)bf16_rn(v.w) << 16);
    *(uint2*)(Bp32 + (size_t)row * 128 + lane * 2) = make_uint2(p0, p1);
    #pragma unroll
    for (int off = 32; off; off >>= 1) s += __shfl_xor(s, off, 64);
    if (lane == 0) wsq[row] = (float)s;
}

// K1b (fallback path): wsq only.
__global__ __launch_bounds__(256) void wsq_kernel(const float* __restrict__ w,
                                                  float* __restrict__ wsq) {
    int wave = threadIdx.x >> 6, lane = threadIdx.x & 63;
    int row = blockIdx.x * 4 + wave;
    float4 v = *(const float4*)(w + (size_t)row * EDIM + lane * 4);
    double s = (double)v.x * v.x + (double)v.y * v.y +
               (double)v.z * v.z + (double)v.w * v.w;
    #pragma unroll
    for (int off = 32; off; off >>= 1) s += __shfl_xor(s, off, 64);
    if (lane == 0) wsq[row] = (float)s;
}

// pack_z: 1024 threads/block; 64-row LDS transpose tile.
__global__ __launch_bounds__(1024) void pack_z(const float* __restrict__ z,
                                               unsigned* __restrict__ Ap32) {
    __shared__ unsigned lds[64 * 129];
    int tid = threadIdx.x;
    int tn = tid & 63, tc = tid >> 6;       // tc in [0,16): 16 d-groups of 16
    int n0 = blockIdx.x * 64;
    int n = n0 + tn;
    int b = n >> 12, lhw = n & 4095;
    #pragma unroll
    for (int cc = 0; cc < 16; cc += 2) {
        int d = tc * 16 + cc;
        float v0 = z[((size_t)b * EDIM + d) * LHW + lhw];
        float v1 = z[((size_t)b * EDIM + d + 1) * LHW + lhw];
        lds[tn * 129 + (d >> 1)] =
            (unsigned)bf16_rn(v0) | ((unsigned)bf16_rn(v1) << 16);
    }
    __syncthreads();
    #pragma unroll
    for (int p = 0; p < 8; ++p) {
        int flat = p * 1024 + tid;          // 64 rows x 128 u32
        int row = flat >> 7, c = flat & 127;
        Ap32[(size_t)(n0 + row) * 128 + c] = lds[row * 129 + c];
    }
}

// K2-MFMA v15: 4-tile software pipeline. v10/v13/v14 showed latency/occupancy
// weren't the wall; the wall is phase-exclusive instruction streams (all waves
// do [MFMA phase][VALU epilogue phase] in cohort lockstep, so the two pipes
// never overlap: MfmaUtil 26% + VALUBusy 34%, elapsed ~2.7x the max-pipe
// floor). Fix: each block runs 4 x-tiles; tile t-1's epilogue is SLICED into
// tile t's chunk phases right after the MFMA cluster (2 j-candidates/phase,
// 16-lane merge at k=3) — the wave issues fire-and-forget MFMAs then
// immediately issues independent epilogue VALU: guaranteed intra-wave
// MFMA||VALU overlap. af is x-independent -> shared across all 4 tiles.
// Double acc (128 AGPR) + wq double-buffer -> ~230 unified regs, 2 waves/SIMD.
// wsq preloaded at k==3 (before stage) so no compiler vmcnt(0) drain; manual
// counts: vmcnt(8) normal, vmcnt(16) at k==3 (8 wq in flight), vmcnt(12) last.
// sched_barrier(0) after slices stops rule-#18 sinking of register-only VALU
// across barriers.
__global__ __launch_bounds__(256, 2) void dist_mfma(const unsigned short* __restrict__ Ap,
                                                    const unsigned short* __restrict__ Bp,
                                                    const float* __restrict__ wsq,
                                                    unsigned* __restrict__ s1) {
    __shared__ __align__(16) unsigned short lds_b[2][128 * 64];   // 2 x 16 KB, swizzled
    int tid = threadIdx.x, lane = tid & 63, w = tid >> 6;
    int xg = blockIdx.x, nt = blockIdx.y;
    int quad = lane >> 4, col = lane & 15;
    int rsel = lane >> 3, seg = lane & 7;   // glds: 8 rows x 8 segs of 16B per call

    const unsigned short* arow = Ap + (size_t)(nt * 128 + w * 32 + col) * 256;

    f32x4 accA[2][8], accB[2][8];
    unsigned m1[2][4], m2[2][4];
    float wqA[8], wqB[8];

    auto stage = [&](int xt, int kc, int bsel) {
        #pragma unroll
        for (int p = 0; p < 4; ++p) {
            int c = w * 4 + p;
            const unsigned short* gb = Bp + (size_t)(xt * 128 + c * 8 + rsel) * 256
                                       + kc * 64 + ((seg ^ (rsel & 7)) * 8);
            __builtin_amdgcn_global_load_lds(
                (const __attribute__((address_space(1))) void*)gb,
                (__attribute__((address_space(3))) void*)(&lds_b[bsel][c * 512]),
                16, 0, 0);
        }
    };

    // process candidates j=jbase..jbase+1 of the PREVIOUS tile into m1/m2
    auto slice2 = [&](const f32x4 (&ap)[2][8], const float (&wqp)[8],
                      int jbase, bool first) {
        if (first) {
            #pragma unroll
            for (int i = 0; i < 2; ++i)
                #pragma unroll
                for (int r = 0; r < 4; ++r) { m1[i][r] = 0xFFFFFFFFu; m2[i][r] = 0xFFFFFFFFu; }
        }
        #pragma unroll
        for (int jo = 0; jo < 2; ++jo) {
            int jj = jbase + jo;
            unsigned jc = (unsigned)(jj * 16 + col);
            float wq = wqp[jj] + 4096.0f;   // d' > 0 -> raw bits u32-sortable
            #pragma unroll
            for (int i = 0; i < 2; ++i)
                #pragma unroll
                for (int r = 0; r < 4; ++r) {
                    float d = fmaf(-2.0f, ap[i][jj][r], wq);
                    unsigned kk = (__float_as_uint(d) & 0xFFFFFF80u) | jc;
                    unsigned mx = (m1[i][r] > kk) ? m1[i][r] : kk;
                    m1[i][r] = (m1[i][r] < kk) ? m1[i][r] : kk;
                    m2[i][r] = (m2[i][r] < mx) ? m2[i][r] : mx;
                }
        }
    };

    auto merge_write = [&](int xt) {
        #pragma unroll
        for (int i = 0; i < 2; ++i)
            #pragma unroll
            for (int r = 0; r < 4; ++r) {
                unsigned a1 = m1[i][r], a2 = m2[i][r];
                #pragma unroll
                for (int off = 1; off < 16; off <<= 1) {
                    unsigned b1 = __shfl_xor(a1, off, 64);
                    unsigned b2 = __shfl_xor(a2, off, 64);
                    unsigned lo1 = a1 < b1 ? a1 : b1;
                    unsigned hi1 = a1 < b1 ? b1 : a1;
                    unsigned lo2 = a2 < b2 ? a2 : b2;
                    a1 = lo1;
                    a2 = hi1 < lo2 ? hi1 : lo2;
                }
                if (col == 0) {
                    int q = nt * 128 + w * 32 + i * 16 + quad * 4 + r;
                    size_t o = (size_t)q * 128 + xt * 2;
                    s1[o] = a1; s1[o + 1] = a2;
                }
            }
    };

    stage(xg * 4, 0, 0);    // prologue: first chunk into buf0

    #pragma unroll
    for (int t = 0; t < 4; ++t) {
        f32x4 (&acc)[2][8]  = (t & 1) ? accB : accA;
        f32x4 (&accp)[2][8] = (t & 1) ? accA : accB;
        float (&wqc)[8] = (t & 1) ? wqB : wqA;
        float (&wqp)[8] = (t & 1) ? wqA : wqB;
        int xt = xg * 4 + t;
        #pragma unroll
        for (int k = 0; k < 4; ++k) {
            int p = t * 4 + k, cur = p & 1;
            if (k == 0) {
                #pragma unroll
                for (int i = 0; i < 2; ++i)
                    #pragma unroll
                    for (int j = 0; j < 8; ++j) acc[i][j] = (f32x4){0.f, 0.f, 0.f, 0.f};
            }
            // af for this chunk: x-independent -> same data for all 4 tiles (L2-hot)
            bf16x8 af[2][2];
            #pragma unroll
            for (int i = 0; i < 2; ++i)
                #pragma unroll
                for (int h = 0; h < 2; ++h)
                    af[i][h] = *(const bf16x8*)(arow + i * 16 * 256 + k * 64 + h * 32 + quad * 8);
            asm volatile("" ::: "memory");   // af above / wq+glds below: pin issue order
            if (k == 3) {
                // preload wsq for THIS tile (consumed by slices during tile t+1);
                // no arithmetic here -> no compiler wait -> prefetch stays in flight
                #pragma unroll
                for (int j = 0; j < 8; ++j)
                    wqc[j] = wsq[xt * 128 + j * 16 + col];
                asm volatile("" ::: "memory");
            }
            bool last = (t == 3 && k == 3);
            if (!last) {
                int t2 = (k == 3) ? t + 1 : t;
                int k2 = (k == 3) ? 0 : k + 1;
                stage(xg * 4 + t2, k2, cur ^ 1);
            }
            asm volatile("" ::: "memory");
            // wait for the CURRENT buffer's glds (issued last phase).
            // newer vmem: af(4) [+wq(8) at k==3] [+glds_next(4) if !last]
            if (k == 3) {
                if (t == 3) asm volatile("s_waitcnt vmcnt(12)" ::: "memory");
                else        asm volatile("s_waitcnt vmcnt(16)" ::: "memory");
            } else {
                asm volatile("s_waitcnt vmcnt(8)" ::: "memory");
            }
            __builtin_amdgcn_s_barrier();    // all waves' glds for cur buffer done
            asm volatile("" ::: "memory");
            __builtin_amdgcn_s_setprio(1);
            #pragma unroll
            for (int h = 0; h < 2; ++h) {
                bf16x8 bf[8];
                #pragma unroll
                for (int j = 0; j < 8; ++j)
                    bf[j] = *(const bf16x8*)(&lds_b[cur][(j * 16 + col) * 64 +
                                             (((h * 4 + quad) ^ (col & 7)) * 8)]);
                #pragma unroll
                for (int i = 0; i < 2; ++i)
                    #pragma unroll
                    for (int j = 0; j < 8; ++j)
                        acc[i][j] = __builtin_amdgcn_mfma_f32_16x16x32_bf16(
                            af[i][h], bf[j], acc[i][j], 0, 0, 0);
            }
            __builtin_amdgcn_s_setprio(0);
            // epilogue slice of tile t-1: pure VALU, no deps on the MFMAs above
            // -> issues while the matrix pipe drains the cluster.
            if (t > 0) {
                slice2(accp, wqp, k * 2, k == 0);
                if (k == 3) merge_write(xt - 1);
            }
            __builtin_amdgcn_sched_barrier(0);   // keep slices in THIS phase
            asm volatile("" ::: "memory");
            if (!last) {
                __builtin_amdgcn_s_barrier();    // buf reuse protection
                asm volatile("" ::: "memory");
            }
        }
    }
    // drain: tile 3's epilogue (parity 1 -> accB/wqB)
    #pragma unroll
    for (int k = 0; k < 4; ++k)
        slice2(accB, wqB, k * 2, k == 0);
    merge_write(xg * 4 + 3);
}

// Refine v2: per block (4 consecutive q = 4 consecutive lhw, same b), the z
// column-gather is cooperatively staged through 4KB LDS; each wave reads its
// q's row conflict-free. Candidate merge + exact fp32 recompute unchanged.
__global__ __launch_bounds__(256) void refine_kernel(const float* __restrict__ z,
                                                     const float* __restrict__ w,
                                                     const float* __restrict__ wsq,
                                                     const unsigned* __restrict__ s1,
                                                     unsigned* __restrict__ idxarr) {
    __shared__ float lds_z[4][260];
    int tid = threadIdx.x, lane = tid & 63, wv = tid >> 6;
    int q0 = blockIdx.x * 4;
    int q = q0 + wv;
    int b = q0 >> 12, lhw0 = q0 & 4095;     // block never crosses a b boundary
    {
        float4 zc = *(const float4*)(z + ((size_t)b * EDIM + tid) * LHW + lhw0);
        lds_z[0][tid] = zc.x; lds_z[1][tid] = zc.y;
        lds_z[2][tid] = zc.z; lds_z[3][tid] = zc.w;
    }
    // slice keys -> global u64 keys: (d_trunc << 13) | e_global
    uint2 kk2 = *(const uint2*)(s1 + (size_t)q * 128 + lane * 2);
    unsigned long long a1 =
        ((unsigned long long)(kk2.x >> 7) << 13) | (unsigned)(lane * 128 + (kk2.x & 127u));
    unsigned long long a2 =
        ((unsigned long long)(kk2.y >> 7) << 13) | (unsigned)(lane * 128 + (kk2.y & 127u));
    #pragma unroll
    for (int off = 1; off < 8; off <<= 1) {
        unsigned long long b1 = __shfl_xor(a1, off, 64);
        unsigned long long b2 = __shfl_xor(a2, off, 64);
        unsigned long long lo1 = a1 < b1 ? a1 : b1;
        unsigned long long hi1 = a1 < b1 ? b1 : a1;
        unsigned long long lo2 = a2 < b2 ? a2 : b2;
        a1 = lo1;
        a2 = hi1 < lo2 ? hi1 : lo2;
    }
    __syncthreads();
    float zv[4];
    #pragma unroll
    for (int t = 0; t < 4; ++t)
        zv[t] = lds_z[wv][lane * 4 + t];
    unsigned long long bestk = ~0ull;
    #pragma unroll
    for (int c = 0; c < 16; ++c) {
        int src = (c >> 1) * 8;
        unsigned long long kc = (c & 1) ? __shfl(a2, src, 64) : __shfl(a1, src, 64);
        unsigned e = (unsigned)(kc & (unsigned long long)(NE - 1));
        float4 wv4 = *(const float4*)(w + (size_t)e * EDIM + lane * 4);
        float p = zv[0] * wv4.x + zv[1] * wv4.y + zv[2] * wv4.z + zv[3] * wv4.w;
        #pragma unroll
        for (int off = 32; off; off >>= 1) p += __shfl_xor(p, off, 64);
        float d = wsq[e] - 2.0f * p;
        unsigned long long key = ((unsigned long long)f32_sortable(d) << 32) | e;
        if (key < bestk) bestk = key;
    }
    if (lane == 0) idxarr[q] = (unsigned)(bestk & 0xFFFFFFFFull);
}

// ---------- fallback fp32 path (used when ws_size < WS_NEED) ----------
__global__ __launch_bounds__(256, 2) void dist_fp32(const float* __restrict__ z,
                                                    const float* __restrict__ w,
                                                    const float* __restrict__ wsq,
                                                    unsigned long long* __restrict__ best) {
    __shared__ float lds_a[32 * 128];
    __shared__ float lds_b[32 * 132];
    int tid = threadIdx.x;
    int tx = tid & 15, ty = tid >> 4;
    int n0 = blockIdx.y * 128;
    int bb_ = n0 >> 12, lhw0 = n0 & 4095;
    const float* zb = z + (size_t)bb_ * (EDIM * LHW) + lhw0;
    int ebase = blockIdx.x * 2048;
    unsigned long long runmin[8];
    #pragma unroll
    for (int i = 0; i < 8; ++i) runmin[i] = ~0ull;
    float acc[64];
    for (int et = 0; et < 16; ++et) {
        int e0 = ebase + et * 128;
        #pragma unroll
        for (int i = 0; i < 64; ++i) acc[i] = 0.f;
        for (int kc = 0; kc < 8; ++kc) {
            int k0 = kc * 32;
            #pragma unroll
            for (int p = 0; p < 4; ++p) {
                int f = p * 256 + tid;
                int kk = f >> 5, nn4 = f & 31;
                float4 v = *(const float4*)(zb + (size_t)(k0 + kk) * LHW + nn4 * 4);
                *((float4*)(lds_a + kk * 128 + nn4 * 4)) = v;
            }
            #pragma unroll
            for (int p = 0; p < 4; ++p) {
                int f = p * 256 + tid;
                int ee = f >> 3, kk4 = f & 7;
                float4 v = *(const float4*)(w + (size_t)(e0 + ee) * EDIM + k0 + kk4 * 4);
                lds_b[(kk4 * 4 + 0) * 132 + ee] = v.x;
                lds_b[(kk4 * 4 + 1) * 132 + ee] = v.y;
                lds_b[(kk4 * 4 + 2) * 132 + ee] = v.z;
                lds_b[(kk4 * 4 + 3) * 132 + ee] = v.w;
            }
            __syncthreads();
            #pragma unroll
            for (int k = 0; k < 32; ++k) {
                float a[8], bv[8];
                *(float4*)(a)      = *(float4*)(lds_a + k * 128 + ty * 8);
                *(float4*)(a + 4)  = *(float4*)(lds_a + k * 128 + ty * 8 + 4);
                *(float4*)(bv)     = *(float4*)(lds_b + k * 132 + tx * 8);
                *(float4*)(bv + 4) = *(float4*)(lds_b + k * 132 + tx * 8 + 4);
                #pragma unroll
                for (int i = 0; i < 8; ++i)
                    #pragma unroll
                    for (int j = 0; j < 8; ++j)
                        acc[i * 8 + j] = fmaf(a[i], bv[j], acc[i * 8 + j]);
            }
            __syncthreads();
        }
        #pragma unroll
        for (int i = 0; i < 8; ++i) {
            unsigned long long m = runmin[i];
            #pragma unroll
            for (int j = 0; j < 8; ++j) {
                int e = e0 + tx * 8 + j;
                float d = wsq[e] - 2.0f * acc[i * 8 + j];
                unsigned long long key =
                    ((unsigned long long)f32_sortable(d) << 32) | (unsigned)e;
                m = (m < key) ? m : key;
            }
            runmin[i] = m;
        }
    }
    #pragma unroll
    for (int i = 0; i < 8; ++i) {
        unsigned long long kk = runmin[i];
        #pragma unroll
        for (int off = 8; off >= 1; off >>= 1) {
            unsigned long long o = __shfl_xor(kk, off, 16);
            kk = (kk < o) ? kk : o;
        }
        if (tx == 0) atomicMin(&best[n0 + ty * 8 + i], kk);
    }
}

__global__ __launch_bounds__(256) void extract_idx(const unsigned long long* __restrict__ best,
                                                   unsigned* __restrict__ idxarr) {
    int n = blockIdx.x * 256 + threadIdx.x;
    idxarr[n] = (unsigned)(best[n] & 0xFFFFFFFFull) & (NE - 1);
}

// K3: 1024 threads/block; loss via LDS block-reduce.
__global__ __launch_bounds__(1024) void gather_kernel(const float* __restrict__ z,
                                                      const float* __restrict__ w,
                                                      const unsigned* __restrict__ idxarr,
                                                      unsigned* __restrict__ counts,
                                                      float* __restrict__ loss,
                                                      float* __restrict__ out,
                                                      float* __restrict__ out_idx) {
    __shared__ int idx_s[64];
    __shared__ float wl[64 * 257];
    __shared__ float lsum[16];
    int tid = threadIdx.x;
    int n0 = blockIdx.x * 64;
    if (tid < 64) {
        int idx = (int)(idxarr[n0 + tid] & (NE - 1));
        idx_s[tid] = idx;
        out_idx[n0 + tid] = (float)idx;
        atomicAdd(&counts[idx], 1u);
    }
    __syncthreads();
    {
        int r0 = tid >> 8, cl = tid & 255;       // 4 row-groups x 256 cols
        #pragma unroll
        for (int i = 0; i < 16; ++i)
            wl[(r0 + i * 4) * 257 + cl] = w[(size_t)idx_s[r0 + i * 4] * EDIM + cl];
    }
    __syncthreads();
    int tn = tid & 63, tc = tid >> 6;            // tc in [0,16): 16 d-groups of 16
    int bb_ = n0 >> 12, lhw0 = n0 & 4095;
    size_t zb = (size_t)bb_ * (EDIM * LHW) + lhw0 + tn;
    float accl = 0.f;
    #pragma unroll
    for (int cc = 0; cc < 16; ++cc) {
        int c = tc * 16 + cc;
        float wv = wl[tn * 257 + c];
        size_t a = zb + (size_t)c * LHW;
        float zv = z[a];
        float diff = wv - zv;            // z_q - zc
        out[a] = zv + diff;              // replicate zc + (z_q - zc) rounding
        accl += diff * diff;
    }
    #pragma unroll
    for (int off = 32; off; off >>= 1) accl += __shfl_xor(accl, off, 64);
    if ((tid & 63) == 0) lsum[tid >> 6] = accl;
    __syncthreads();
    if (tid < 16) {
        float v = lsum[tid];
        v += __shfl_xor(v, 8, 16);
        v += __shfl_xor(v, 4, 16);
        v += __shfl_xor(v, 2, 16);
        v += __shfl_xor(v, 1, 16);
        if (tid == 0) atomicAdd(loss, v);
    }
}

// K4: scalars
__global__ __launch_bounds__(256) void finalize_kernel(const unsigned* __restrict__ counts,
                                                       const float* __restrict__ loss,
                                                       float* __restrict__ out_scalars) {
    __shared__ float ss[4];
    __shared__ int uu[4];
    int tid = threadIdx.x;
    float s = 0.f;
    int uniq = 0;
    for (int i = tid; i < NE; i += 256) {
        unsigned c = counts[i];
        if (c > 0) {
            float p = (float)c * (1.0f / (float)NQ);
            s += p * logf(p + 1e-10f);
            uniq++;
        }
    }
    #pragma unroll
    for (int off = 32; off; off >>= 1) {
        s += __shfl_xor(s, off, 64);
        uniq += __shfl_xor(uniq, off, 64);
    }
    int wave = tid >> 6;
    if ((tid & 63) == 0) { ss[wave] = s; uu[wave] = uniq; }
    __syncthreads();
    if (tid == 0) {
        float st = ss[0] + ss[1] + ss[2] + ss[3];
        int ut = uu[0] + uu[1] + uu[2] + uu[3];
        out_scalars[0] = BETA * loss[0] * (1.0f / (float)(NQ * EDIM));  // loss
        out_scalars[1] = expf(-st);                                     // perplexity
        out_scalars[2] = (float)ut;                                     // unique
    }
}

extern "C" void kernel_launch(void* const* d_in, const int* in_sizes, int n_in,
                              void* d_out, int out_size, void* d_ws, size_t ws_size,
                              hipStream_t stream) {
    const float* z = (const float*)d_in[0];
    const float* w = (const float*)d_in[1];
    float* out = (float*)d_out;
    char* ws = (char*)d_ws;
    float* wsq = (float*)(ws + WS_WSQ);
    unsigned* counts = (unsigned*)(ws + WS_CNT);
    float* loss = (float*)(ws + WS_LOSS);
    unsigned* idxarr = (unsigned*)(ws + WS_IDX);
    unsigned long long* best = (unsigned long long*)(ws + WS_BEST);
    unsigned* Ap = (unsigned*)(ws + WS_APACK);
    unsigned* Bp = (unsigned*)(ws + WS_BPACK);

    int idx_off = out_size - NQ;
    int scal_off = idx_off - 3;
    float* out_idx = out + idx_off;
    float* out_scalars = out + scal_off;

    // z_q region of d_out doubles as the per-slice top-2 scratch (u32 keys,
    // written by dist_mfma, read by refine, overwritten by gather).
    unsigned* s1 = (unsigned*)out;

    if (ws_size >= (size_t)WS_NEED) {
        wsq_pack_w<<<NE / 4, 256, 0, stream>>>(w, wsq, Bp, counts, loss);
        pack_z<<<NQ / 64, 1024, 0, stream>>>(z, Ap);
        dist_mfma<<<dim3(16, 128), 256, 0, stream>>>((const unsigned short*)Ap,
                                                     (const unsigned short*)Bp, wsq, s1);
        refine_kernel<<<NQ / 4, 256, 0, stream>>>(z, w, wsq, s1, idxarr);
    } else {
        hipMemsetAsync(counts, 0, NE * sizeof(unsigned), stream);
        hipMemsetAsync(loss, 0, sizeof(float), stream);
        wsq_kernel<<<NE / 4, 256, 0, stream>>>(w, wsq);
        hipMemsetAsync(best, 0xFF, NQ * sizeof(unsigned long long), stream);
        dist_fp32<<<dim3(4, 128), 256, 0, stream>>>(z, w, wsq, best);
        extract_idx<<<NQ / 256, 256, 0, stream>>>(best, idxarr);
    }

    gather_kernel<<<NQ / 64, 1024, 0, stream>>>(z, w, idxarr, counts, loss, out, out_idx);
    finalize_kernel<<<1, 256, 0, stream>>>(counts, loss, out_scalars);
}

// Round 7
// 238.884 us; speedup vs baseline: 1.1174x; 1.1174x over previous
//
#include <hip/hip_runtime.h>

// Problem constants
#define NQ     16384       // 4*16*16*16 query vectors
#define EDIM   256
#define NE     8192
#define LHW    4096        // 16*16*16
#define BETA   0.25f

// ws layout (bytes) — K=256 bf16-hi packing.
#define WS_WSQ    0            // f32[NE]             32768
#define WS_CNT    32768        // u32[NE]             32768
#define WS_LOSS   65536        // f32 loss; +4: u32 done-counter; (256B pad)
#define WS_IDX    65792        // u32[NQ]             65536
#define WS_BEST   131328       // u64[NQ] (fallback)  131072
#define WS_APACK  2359552      // ushort[NQ*256]      8388608
#define WS_BPACK  10748160     // ushort[NE*256]      4194304
#define WS_NEED   14942464

typedef __attribute__((ext_vector_type(8))) short bf16x8;
typedef __attribute__((ext_vector_type(4))) float f32x4;

__device__ __forceinline__ unsigned f32_sortable(float f) {
    unsigned b = __float_as_uint(f);
    return b ^ ((unsigned)((int)b >> 31) | 0x80000000u);   // 3 VALU ops
}
__device__ __forceinline__ unsigned short bf16_rn(float f) {
    unsigned u = __float_as_uint(f);
    return (unsigned short)((u + 0x7FFFu + ((u >> 16) & 1u)) >> 16);
}

// pack_all: fused wsq+pack_w (blocks 0..511, 16 rows each) and pack_z
// (blocks 512..767). The two phases are independent; fusing removes one
// launch gap and runs the small w-pack concurrently with the z-pack.
// Blocks 0..7 also zero counts; block 0 zeroes loss + done.
__global__ __launch_bounds__(1024) void pack_all(const float* __restrict__ w,
                                                 const float* __restrict__ z,
                                                 float* __restrict__ wsq,
                                                 unsigned* __restrict__ Bp32,
                                                 unsigned* __restrict__ Ap32,
                                                 unsigned* __restrict__ counts,
                                                 float* __restrict__ loss,
                                                 unsigned* __restrict__ done) {
    __shared__ unsigned lds[64 * 129];
    int tid = threadIdx.x;
    if (blockIdx.x < 512) {
        // ---- w part: 16 waves, one codebook row per wave ----
        int wave = tid >> 6, lane = tid & 63;
        int row = blockIdx.x * 16 + wave;
        if (blockIdx.x < 8) {
            counts[blockIdx.x * 1024 + tid] = 0u;
            if (blockIdx.x == 0 && tid == 0) { loss[0] = 0.f; done[0] = 0u; }
        }
        float4 v = *(const float4*)(w + (size_t)row * EDIM + lane * 4);
        double s = (double)v.x * v.x + (double)v.y * v.y +
                   (double)v.z * v.z + (double)v.w * v.w;
        unsigned p0 = (unsigned)bf16_rn(v.x) | ((unsigned)bf16_rn(v.y) << 16);
        unsigned p1 = (unsigned)bf16_rn(v.z) | ((unsigned)bf16_rn(v.w) << 16);
        *(uint2*)(Bp32 + (size_t)row * 128 + lane * 2) = make_uint2(p0, p1);
        #pragma unroll
        for (int off = 32; off; off >>= 1) s += __shfl_xor(s, off, 64);
        if (lane == 0) wsq[row] = (float)s;
    } else {
        // ---- z part: 64-row LDS transpose tile (identical to prior pack_z) ----
        int bz = blockIdx.x - 512;
        int tn = tid & 63, tc = tid >> 6;       // tc in [0,16): 16 d-groups of 16
        int n0 = bz * 64;
        int n = n0 + tn;
        int b = n >> 12, lhw = n & 4095;
        #pragma unroll
        for (int cc = 0; cc < 16; cc += 2) {
            int d = tc * 16 + cc;
            float v0 = z[((size_t)b * EDIM + d) * LHW + lhw];
            float v1 = z[((size_t)b * EDIM + d + 1) * LHW + lhw];
            lds[tn * 129 + (d >> 1)] =
                (unsigned)bf16_rn(v0) | ((unsigned)bf16_rn(v1) << 16);
        }
        __syncthreads();
        #pragma unroll
        for (int p = 0; p < 8; ++p) {
            int flat = p * 1024 + tid;          // 64 rows x 128 u32
            int row = flat >> 7, c = flat & 127;
            Ap32[(size_t)(n0 + row) * 128 + c] = lds[row * 129 + c];
        }
    }
}

// K1b (fallback path): wsq only.
__global__ __launch_bounds__(256) void wsq_kernel(const float* __restrict__ w,
                                                  float* __restrict__ wsq) {
    int wave = threadIdx.x >> 6, lane = threadIdx.x & 63;
    int row = blockIdx.x * 4 + wave;
    float4 v = *(const float4*)(w + (size_t)row * EDIM + lane * 4);
    double s = (double)v.x * v.x + (double)v.y * v.y +
               (double)v.z * v.z + (double)v.w * v.w;
    #pragma unroll
    for (int off = 32; off; off >>= 1) s += __shfl_xor(s, off, 64);
    if (lane == 0) wsq[row] = (float)s;
}

// K2-MFMA v14 (proven 112 µs, reverted from v15's spilling pipeline):
// wave tile 32n x 128e, acc[2][8] = 64 AGPR, __launch_bounds__(256,3) ->
// 3 blocks/CU; BK=64 dbuf LDS, r10 XOR swizzle (0 conflicts), counted vmcnt
// (af(4)+glds_next(4)=8 in-loop; af(4)=4 last chunk), setprio around MFMA.
__global__ __launch_bounds__(256, 3) void dist_mfma(const unsigned short* __restrict__ Ap,
                                                    const unsigned short* __restrict__ Bp,
                                                    const float* __restrict__ wsq,
                                                    unsigned* __restrict__ s1) {
    __shared__ __align__(16) unsigned short lds_b[2][128 * 64];   // 2 x 16 KB, swizzled
    int tid = threadIdx.x, lane = tid & 63, w = tid >> 6;
    int x = blockIdx.x, nt = blockIdx.y;
    int quad = lane >> 4, col = lane & 15;
    int rsel = lane >> 3, seg = lane & 7;   // glds: 8 rows x 8 segs of 16B per call

    const unsigned short* arow = Ap + (size_t)(nt * 128 + w * 32 + col) * 256;
    const unsigned short* Bbase = Bp + (size_t)(x * 128) * 256;

    f32x4 acc[2][8];
    #pragma unroll
    for (int i = 0; i < 2; ++i)
        #pragma unroll
        for (int j = 0; j < 8; ++j) acc[i][j] = (f32x4){0.f, 0.f, 0.f, 0.f};

    // stage B chunk kc into lds_b[bsel]: 16 calls of 1KB (4/wave), r10 swizzle.
    auto stage_chunk = [&](int kc, int bsel) {
        int k0s = kc * 64;
        #pragma unroll
        for (int p = 0; p < 4; ++p) {
            int c = w * 4 + p;
            const unsigned short* gb =
                Bbase + (size_t)(c * 8 + rsel) * 256 + k0s + ((seg ^ (rsel & 7)) * 8);
            __builtin_amdgcn_global_load_lds(
                (const __attribute__((address_space(1))) void*)gb,
                (__attribute__((address_space(3))) void*)(&lds_b[bsel][c * 512]),
                16, 0, 0);
        }
    };

    // prologue: stage chunk 0 into buffer 0 (no barrier needed; LDS unread yet)
    stage_chunk(0, 0);

    #pragma unroll
    for (int kcc = 0; kcc < 4; ++kcc) {
        int k0 = kcc * 64;
        int cur = kcc & 1;
        // A frags for this chunk: global -> VGPR (L2-resident tile), issued
        // before the next-chunk glds.
        bf16x8 af[2][2];
        #pragma unroll
        for (int i = 0; i < 2; ++i)
            #pragma unroll
            for (int h = 0; h < 2; ++h)
                af[i][h] = *(const bf16x8*)(arow + i * 16 * 256 + k0 + h * 32 + quad * 8);
        asm volatile("" ::: "memory");   // af above / glds below: fixes issue order
        if (kcc < 3) {
            stage_chunk(kcc + 1, cur ^ 1);
            // wait for MY glds of the CURRENT buffer (issued last iter):
            // newer vmem ops = af(4) + glds_next(4) = 8 (in-order retirement).
            asm volatile("s_waitcnt vmcnt(8)" ::: "memory");
        } else {
            // no prefetch issued: newer ops = af(4) only.
            asm volatile("s_waitcnt vmcnt(4)" ::: "memory");
        }
        __builtin_amdgcn_s_barrier();    // all waves' glds for cur buffer done
        asm volatile("" ::: "memory");   // ds_reads must not hoist above barrier
        __builtin_amdgcn_s_setprio(1);
        #pragma unroll
        for (int h = 0; h < 2; ++h) {
            bf16x8 bf[8];
            #pragma unroll
            for (int j = 0; j < 8; ++j)
                bf[j] = *(const bf16x8*)(&lds_b[cur][(j * 16 + col) * 64 +
                                         (((h * 4 + quad) ^ (col & 7)) * 8)]);
            #pragma unroll
            for (int i = 0; i < 2; ++i)
                #pragma unroll
                for (int j = 0; j < 8; ++j)
                    acc[i][j] = __builtin_amdgcn_mfma_f32_16x16x32_bf16(
                        af[i][h], bf[j], acc[i][j], 0, 0, 0);
        }
        __builtin_amdgcn_s_setprio(0);
        asm volatile("" ::: "memory");   // ds_reads/MFMA stay above the barrier
        if (kcc < 3) {
            // all waves done reading lds_b[cur] before next iter's glds
            // overwrite it (next iter stages chunk kcc+2 into buffer cur).
            __builtin_amdgcn_s_barrier();
            asm volatile("" ::: "memory");   // next glds must not hoist above
        }
    }

    // epilogue: d' = (wsq[e]+4096) - 2*dot  (always positive) -> raw float
    // bits are u32-sortable. key = (bits & ~0x7F) | e_local. Branchless top-2,
    // then cross-lane merge over 16 e-lanes. 64 candidates/thread.
    unsigned m1[2][4], m2[2][4];
    #pragma unroll
    for (int i = 0; i < 2; ++i)
        #pragma unroll
        for (int r = 0; r < 4; ++r) { m1[i][r] = 0xFFFFFFFFu; m2[i][r] = 0xFFFFFFFFu; }
    #pragma unroll
    for (int j = 0; j < 8; ++j) {
        int e = x * 128 + j * 16 + col;
        unsigned jc = (unsigned)(j * 16 + col);   // e_local, 7 bits
        float wq_off = wsq[e] + 4096.0f;
        #pragma unroll
        for (int i = 0; i < 2; ++i)
            #pragma unroll
            for (int r = 0; r < 4; ++r) {
                float d = fmaf(-2.0f, acc[i][j][r], wq_off);
                unsigned k = (__float_as_uint(d) & 0xFFFFFF80u) | jc;
                unsigned mx = (m1[i][r] > k) ? m1[i][r] : k;
                m1[i][r] = (m1[i][r] < k) ? m1[i][r] : k;
                m2[i][r] = (m2[i][r] < mx) ? m2[i][r] : mx;
            }
    }
    #pragma unroll
    for (int i = 0; i < 2; ++i)
        #pragma unroll
        for (int r = 0; r < 4; ++r) {
            unsigned a1 = m1[i][r], a2 = m2[i][r];
            #pragma unroll
            for (int off = 1; off < 16; off <<= 1) {
                unsigned b1 = __shfl_xor(a1, off, 64);
                unsigned b2 = __shfl_xor(a2, off, 64);
                unsigned lo1 = a1 < b1 ? a1 : b1;
                unsigned hi1 = a1 < b1 ? b1 : a1;
                unsigned lo2 = a2 < b2 ? a2 : b2;
                a1 = lo1;
                a2 = hi1 < lo2 ? hi1 : lo2;
            }
            if (col == 0) {
                int q = nt * 128 + w * 32 + i * 16 + quad * 4 + r;
                size_t o = (size_t)q * 128 + x * 2;
                s1[o] = a1; s1[o + 1] = a2;
            }
        }
}

// Refine: per block (4 consecutive q = 4 consecutive lhw, same b), the z
// column-gather is cooperatively staged through 4KB LDS; each wave reads its
// q's row conflict-free. 16 candidates, exact fp32 recompute, true argmin.
__global__ __launch_bounds__(256) void refine_kernel(const float* __restrict__ z,
                                                     const float* __restrict__ w,
                                                     const float* __restrict__ wsq,
                                                     const unsigned* __restrict__ s1,
                                                     unsigned* __restrict__ idxarr) {
    __shared__ float lds_z[4][260];
    int tid = threadIdx.x, lane = tid & 63, wv = tid >> 6;
    int q0 = blockIdx.x * 4;
    int q = q0 + wv;
    int b = q0 >> 12, lhw0 = q0 & 4095;     // block never crosses a b boundary
    {
        float4 zc = *(const float4*)(z + ((size_t)b * EDIM + tid) * LHW + lhw0);
        lds_z[0][tid] = zc.x; lds_z[1][tid] = zc.y;
        lds_z[2][tid] = zc.z; lds_z[3][tid] = zc.w;
    }
    // slice keys -> global u64 keys: (d_trunc << 13) | e_global
    uint2 kk2 = *(const uint2*)(s1 + (size_t)q * 128 + lane * 2);
    unsigned long long a1 =
        ((unsigned long long)(kk2.x >> 7) << 13) | (unsigned)(lane * 128 + (kk2.x & 127u));
    unsigned long long a2 =
        ((unsigned long long)(kk2.y >> 7) << 13) | (unsigned)(lane * 128 + (kk2.y & 127u));
    #pragma unroll
    for (int off = 1; off < 8; off <<= 1) {
        unsigned long long b1 = __shfl_xor(a1, off, 64);
        unsigned long long b2 = __shfl_xor(a2, off, 64);
        unsigned long long lo1 = a1 < b1 ? a1 : b1;
        unsigned long long hi1 = a1 < b1 ? b1 : a1;
        unsigned long long lo2 = a2 < b2 ? a2 : b2;
        a1 = lo1;
        a2 = hi1 < lo2 ? hi1 : lo2;
    }
    __syncthreads();
    float zv[4];
    #pragma unroll
    for (int t = 0; t < 4; ++t)
        zv[t] = lds_z[wv][lane * 4 + t];
    unsigned long long bestk = ~0ull;
    #pragma unroll
    for (int c = 0; c < 16; ++c) {
        int src = (c >> 1) * 8;
        unsigned long long kc = (c & 1) ? __shfl(a2, src, 64) : __shfl(a1, src, 64);
        unsigned e = (unsigned)(kc & (unsigned long long)(NE - 1));
        float4 wv4 = *(const float4*)(w + (size_t)e * EDIM + lane * 4);
        float p = zv[0] * wv4.x + zv[1] * wv4.y + zv[2] * wv4.z + zv[3] * wv4.w;
        #pragma unroll
        for (int off = 32; off; off >>= 1) p += __shfl_xor(p, off, 64);
        float d = wsq[e] - 2.0f * p;
        unsigned long long key = ((unsigned long long)f32_sortable(d) << 32) | e;
        if (key < bestk) bestk = key;
    }
    if (lane == 0) idxarr[q] = (unsigned)(bestk & 0xFFFFFFFFull);
}

// ---------- fallback fp32 path (used when ws_size < WS_NEED) ----------
__global__ __launch_bounds__(256, 2) void dist_fp32(const float* __restrict__ z,
                                                    const float* __restrict__ w,
                                                    const float* __restrict__ wsq,
                                                    unsigned long long* __restrict__ best) {
    __shared__ float lds_a[32 * 128];
    __shared__ float lds_b[32 * 132];
    int tid = threadIdx.x;
    int tx = tid & 15, ty = tid >> 4;
    int n0 = blockIdx.y * 128;
    int bb_ = n0 >> 12, lhw0 = n0 & 4095;
    const float* zb = z + (size_t)bb_ * (EDIM * LHW) + lhw0;
    int ebase = blockIdx.x * 2048;
    unsigned long long runmin[8];
    #pragma unroll
    for (int i = 0; i < 8; ++i) runmin[i] = ~0ull;
    float acc[64];
    for (int et = 0; et < 16; ++et) {
        int e0 = ebase + et * 128;
        #pragma unroll
        for (int i = 0; i < 64; ++i) acc[i] = 0.f;
        for (int kc = 0; kc < 8; ++kc) {
            int k0 = kc * 32;
            #pragma unroll
            for (int p = 0; p < 4; ++p) {
                int f = p * 256 + tid;
                int kk = f >> 5, nn4 = f & 31;
                float4 v = *(const float4*)(zb + (size_t)(k0 + kk) * LHW + nn4 * 4);
                *((float4*)(lds_a + kk * 128 + nn4 * 4)) = v;
            }
            #pragma unroll
            for (int p = 0; p < 4; ++p) {
                int f = p * 256 + tid;
                int ee = f >> 3, kk4 = f & 7;
                float4 v = *(const float4*)(w + (size_t)(e0 + ee) * EDIM + k0 + kk4 * 4);
                lds_b[(kk4 * 4 + 0) * 132 + ee] = v.x;
                lds_b[(kk4 * 4 + 1) * 132 + ee] = v.y;
                lds_b[(kk4 * 4 + 2) * 132 + ee] = v.z;
                lds_b[(kk4 * 4 + 3) * 132 + ee] = v.w;
            }
            __syncthreads();
            #pragma unroll
            for (int k = 0; k < 32; ++k) {
                float a[8], bv[8];
                *(float4*)(a)      = *(float4*)(lds_a + k * 128 + ty * 8);
                *(float4*)(a + 4)  = *(float4*)(lds_a + k * 128 + ty * 8 + 4);
                *(float4*)(bv)     = *(float4*)(lds_b + k * 132 + tx * 8);
                *(float4*)(bv + 4) = *(float4*)(lds_b + k * 132 + tx * 8 + 4);
                #pragma unroll
                for (int i = 0; i < 8; ++i)
                    #pragma unroll
                    for (int j = 0; j < 8; ++j)
                        acc[i * 8 + j] = fmaf(a[i], bv[j], acc[i * 8 + j]);
            }
            __syncthreads();
        }
        #pragma unroll
        for (int i = 0; i < 8; ++i) {
            unsigned long long m = runmin[i];
            #pragma unroll
            for (int j = 0; j < 8; ++j) {
                int e = e0 + tx * 8 + j;
                float d = wsq[e] - 2.0f * acc[i * 8 + j];
                unsigned long long key =
                    ((unsigned long long)f32_sortable(d) << 32) | (unsigned)e;
                m = (m < key) ? m : key;
            }
            runmin[i] = m;
        }
    }
    #pragma unroll
    for (int i = 0; i < 8; ++i) {
        unsigned long long kk = runmin[i];
        #pragma unroll
        for (int off = 8; off >= 1; off >>= 1) {
            unsigned long long o = __shfl_xor(kk, off, 16);
            kk = (kk < o) ? kk : o;
        }
        if (tx == 0) atomicMin(&best[n0 + ty * 8 + i], kk);
    }
}

__global__ __launch_bounds__(256) void extract_idx(const unsigned long long* __restrict__ best,
                                                   unsigned* __restrict__ idxarr) {
    int n = blockIdx.x * 256 + threadIdx.x;
    idxarr[n] = (unsigned)(best[n] & 0xFFFFFFFFull) & (NE - 1);
}

// K3: gather + fused finalize (last-block pattern). 1024 threads/block.
// After each block's count/loss atomics complete (__syncthreads drains them),
// tid0 does a release fence + atomicAdd(done); the block that observes
// NQ/64-1 acquire-fences (L1 invalidate) and computes the scalars.
__global__ __launch_bounds__(1024) void gather_kernel(const float* __restrict__ z,
                                                      const float* __restrict__ w,
                                                      const unsigned* __restrict__ idxarr,
                                                      unsigned* __restrict__ counts,
                                                      float* __restrict__ loss,
                                                      unsigned* __restrict__ done,
                                                      float* __restrict__ out,
                                                      float* __restrict__ out_idx,
                                                      float* __restrict__ out_scalars) {
    __shared__ int idx_s[64];
    __shared__ float wl[64 * 257];
    __shared__ float lsum[16];
    __shared__ int usum[16];
    __shared__ unsigned lastflag;
    int tid = threadIdx.x;
    int n0 = blockIdx.x * 64;
    if (tid < 64) {
        int idx = (int)(idxarr[n0 + tid] & (NE - 1));
        idx_s[tid] = idx;
        out_idx[n0 + tid] = (float)idx;
        atomicAdd(&counts[idx], 1u);
    }
    __syncthreads();
    {
        int r0 = tid >> 8, cl = tid & 255;       // 4 row-groups x 256 cols
        #pragma unroll
        for (int i = 0; i < 16; ++i)
            wl[(r0 + i * 4) * 257 + cl] = w[(size_t)idx_s[r0 + i * 4] * EDIM + cl];
    }
    __syncthreads();
    int tn = tid & 63, tc = tid >> 6;            // tc in [0,16): 16 d-groups of 16
    int bb_ = n0 >> 12, lhw0 = n0 & 4095;
    size_t zb = (size_t)bb_ * (EDIM * LHW) + lhw0 + tn;
    float accl = 0.f;
    #pragma unroll
    for (int cc = 0; cc < 16; ++cc) {
        int c = tc * 16 + cc;
        float wv = wl[tn * 257 + c];
        size_t a = zb + (size_t)c * LHW;
        float zv = z[a];
        float diff = wv - zv;            // z_q - zc
        out[a] = zv + diff;              // replicate zc + (z_q - zc) rounding
        accl += diff * diff;
    }
    #pragma unroll
    for (int off = 32; off; off >>= 1) accl += __shfl_xor(accl, off, 64);
    if ((tid & 63) == 0) lsum[tid >> 6] = accl;
    __syncthreads();
    if (tid < 16) {
        float v = lsum[tid];
        v += __shfl_xor(v, 8, 16);
        v += __shfl_xor(v, 4, 16);
        v += __shfl_xor(v, 2, 16);
        v += __shfl_xor(v, 1, 16);
        if (tid == 0) atomicAdd(loss, v);
    }
    // ---- fused finalize: last block computes the scalars ----
    __syncthreads();                     // all this block's atomics are issued+drained
    if (tid == 0) {
        __threadfence();                 // release: counts/loss visible device-wide
        lastflag = (atomicAdd(done, 1u) == (unsigned)(NQ / 64 - 1));
    }
    __syncthreads();
    if (lastflag) {
        __threadfence();                 // acquire: invalidate L1, see all blocks' data
        float s = 0.f;
        int uniq = 0;
        for (int i = tid; i < NE; i += 1024) {
            unsigned c = counts[i];
            if (c > 0) {
                float p = (float)c * (1.0f / (float)NQ);
                s += p * logf(p + 1e-10f);
                uniq++;
            }
        }
        #pragma unroll
        for (int off = 32; off; off >>= 1) {
            s += __shfl_xor(s, off, 64);
            uniq += __shfl_xor(uniq, off, 64);
        }
        if ((tid & 63) == 0) { lsum[tid >> 6] = s; usum[tid >> 6] = uniq; }
        __syncthreads();
        if (tid == 0) {
            float st = 0.f;
            int ut = 0;
            #pragma unroll
            for (int i = 0; i < 16; ++i) { st += lsum[i]; ut += usum[i]; }
            out_scalars[0] = BETA * loss[0] * (1.0f / (float)(NQ * EDIM));  // loss
            out_scalars[1] = expf(-st);                                     // perplexity
            out_scalars[2] = (float)ut;                                     // unique
        }
    }
}

extern "C" void kernel_launch(void* const* d_in, const int* in_sizes, int n_in,
                              void* d_out, int out_size, void* d_ws, size_t ws_size,
                              hipStream_t stream) {
    const float* z = (const float*)d_in[0];
    const float* w = (const float*)d_in[1];
    float* out = (float*)d_out;
    char* ws = (char*)d_ws;
    float* wsq = (float*)(ws + WS_WSQ);
    unsigned* counts = (unsigned*)(ws + WS_CNT);
    float* loss = (float*)(ws + WS_LOSS);
    unsigned* done = (unsigned*)(ws + WS_LOSS + 4);
    unsigned* idxarr = (unsigned*)(ws + WS_IDX);
    unsigned long long* best = (unsigned long long*)(ws + WS_BEST);
    unsigned* Ap = (unsigned*)(ws + WS_APACK);
    unsigned* Bp = (unsigned*)(ws + WS_BPACK);

    int idx_off = out_size - NQ;
    int scal_off = idx_off - 3;
    float* out_idx = out + idx_off;
    float* out_scalars = out + scal_off;

    // z_q region of d_out doubles as the per-slice top-2 scratch (u32 keys,
    // written by dist_mfma, read by refine, overwritten by gather).
    unsigned* s1 = (unsigned*)out;

    if (ws_size >= (size_t)WS_NEED) {
        pack_all<<<768, 1024, 0, stream>>>(w, z, wsq, Bp, Ap, counts, loss, done);
        dist_mfma<<<dim3(64, 128), 256, 0, stream>>>((const unsigned short*)Ap,
                                                     (const unsigned short*)Bp, wsq, s1);
        refine_kernel<<<NQ / 4, 256, 0, stream>>>(z, w, wsq, s1, idxarr);
    } else {
        hipMemsetAsync(counts, 0, NE * sizeof(unsigned), stream);
        hipMemsetAsync(loss, 0, 8, stream);   // loss + done
        wsq_kernel<<<NE / 4, 256, 0, stream>>>(w, wsq);
        hipMemsetAsync(best, 0xFF, NQ * sizeof(unsigned long long), stream);
        dist_fp32<<<dim3(4, 128), 256, 0, stream>>>(z, w, wsq, best);
        extract_idx<<<NQ / 256, 256, 0, stream>>>(best, idxarr);
    }

    gather_kernel<<<NQ / 64, 1024, 0, stream>>>(z, w, idxarr, counts, loss, done,
                                                out, out_idx, out_scalars);
}

// Round 8
// 220.041 us; speedup vs baseline: 1.2131x; 1.0856x over previous
//
#include <hip/hip_runtime.h>

// Problem constants
#define NQ     16384       // 4*16*16*16 query vectors
#define EDIM   256
#define NE     8192
#define LHW    4096        // 16*16*16
#define BETA   0.25f

// ws layout (bytes) — K=256 bf16-hi packing; s1 now lives in ws (it used to
// alias d_out, which is illegal once refine+gather are fused into one kernel).
#define WS_WSQ    0            // f32[NE]             32768
#define WS_CNT    32768        // u32[NE]             32768
#define WS_LOSS   65536        // f32 loss; +4: u32 done-counter; (256B pad)
#define WS_IDX    65792        // u32[NQ]             65536
#define WS_BEST   131328       // u64[NQ] (fallback)  131072
#define WS_APACK  2359552      // ushort[NQ*256]      8388608
#define WS_BPACK  10748160     // ushort[NE*256]      4194304
#define WS_S1     14942464     // u32[64][NQ][2]      8388608   (slice-major!)
#define WS_NEED   23331072

typedef __attribute__((ext_vector_type(8))) short bf16x8;
typedef __attribute__((ext_vector_type(4))) float f32x4;

__device__ __forceinline__ unsigned f32_sortable(float f) {
    unsigned b = __float_as_uint(f);
    return b ^ ((unsigned)((int)b >> 31) | 0x80000000u);   // 3 VALU ops
}
__device__ __forceinline__ unsigned short bf16_rn(float f) {
    unsigned u = __float_as_uint(f);
    return (unsigned short)((u + 0x7FFFu + ((u >> 16) & 1u)) >> 16);
}

// pack_all: fused wsq+pack_w (blocks 0..511, 16 rows each) and pack_z
// (blocks 512..767). Blocks 0..7 zero counts; block 0 zeroes loss + done.
__global__ __launch_bounds__(1024) void pack_all(const float* __restrict__ w,
                                                 const float* __restrict__ z,
                                                 float* __restrict__ wsq,
                                                 unsigned* __restrict__ Bp32,
                                                 unsigned* __restrict__ Ap32,
                                                 unsigned* __restrict__ counts,
                                                 float* __restrict__ loss,
                                                 unsigned* __restrict__ done) {
    __shared__ unsigned lds[64 * 129];
    int tid = threadIdx.x;
    if (blockIdx.x < 512) {
        // ---- w part: 16 waves, one codebook row per wave ----
        int wave = tid >> 6, lane = tid & 63;
        int row = blockIdx.x * 16 + wave;
        if (blockIdx.x < 8) {
            counts[blockIdx.x * 1024 + tid] = 0u;
            if (blockIdx.x == 0 && tid == 0) { loss[0] = 0.f; done[0] = 0u; }
        }
        float4 v = *(const float4*)(w + (size_t)row * EDIM + lane * 4);
        double s = (double)v.x * v.x + (double)v.y * v.y +
                   (double)v.z * v.z + (double)v.w * v.w;
        unsigned p0 = (unsigned)bf16_rn(v.x) | ((unsigned)bf16_rn(v.y) << 16);
        unsigned p1 = (unsigned)bf16_rn(v.z) | ((unsigned)bf16_rn(v.w) << 16);
        *(uint2*)(Bp32 + (size_t)row * 128 + lane * 2) = make_uint2(p0, p1);
        #pragma unroll
        for (int off = 32; off; off >>= 1) s += __shfl_xor(s, off, 64);
        if (lane == 0) wsq[row] = (float)s;
    } else {
        // ---- z part: 64-row LDS transpose tile ----
        int bz = blockIdx.x - 512;
        int tn = tid & 63, tc = tid >> 6;       // tc in [0,16): 16 d-groups of 16
        int n0 = bz * 64;
        int n = n0 + tn;
        int b = n >> 12, lhw = n & 4095;
        #pragma unroll
        for (int cc = 0; cc < 16; cc += 2) {
            int d = tc * 16 + cc;
            float v0 = z[((size_t)b * EDIM + d) * LHW + lhw];
            float v1 = z[((size_t)b * EDIM + d + 1) * LHW + lhw];
            lds[tn * 129 + (d >> 1)] =
                (unsigned)bf16_rn(v0) | ((unsigned)bf16_rn(v1) << 16);
        }
        __syncthreads();
        #pragma unroll
        for (int p = 0; p < 8; ++p) {
            int flat = p * 1024 + tid;          // 64 rows x 128 u32
            int row = flat >> 7, c = flat & 127;
            Ap32[(size_t)(n0 + row) * 128 + c] = lds[row * 129 + c];
        }
    }
}

// K1b (fallback path): wsq only.
__global__ __launch_bounds__(256) void wsq_kernel(const float* __restrict__ w,
                                                  float* __restrict__ wsq) {
    int wave = threadIdx.x >> 6, lane = threadIdx.x & 63;
    int row = blockIdx.x * 4 + wave;
    float4 v = *(const float4*)(w + (size_t)row * EDIM + lane * 4);
    double s = (double)v.x * v.x + (double)v.y * v.y +
               (double)v.z * v.z + (double)v.w * v.w;
    #pragma unroll
    for (int off = 32; off; off >>= 1) s += __shfl_xor(s, off, 64);
    if (lane == 0) wsq[row] = (float)s;
}

// K2-MFMA (v14 pipeline, proven 112-113 µs): wave tile 32n x 128e, acc[2][8],
// 3 blocks/CU, BK=64 dbuf LDS, r10 XOR swizzle, counted vmcnt, setprio.
// v17 change: s1 is SLICE-MAJOR [x][q][2] in ws — each block's epilogue writes
// a contiguous 1 KB run (was 8-B fragments at stride 512 B across 64 blocks on
// different XCDs -> 4x HBM write amplification, WRITE_SIZE 32 MB for 8.4 MB).
__global__ __launch_bounds__(256, 3) void dist_mfma(const unsigned short* __restrict__ Ap,
                                                    const unsigned short* __restrict__ Bp,
                                                    const float* __restrict__ wsq,
                                                    unsigned* __restrict__ s1) {
    __shared__ __align__(16) unsigned short lds_b[2][128 * 64];   // 2 x 16 KB, swizzled
    int tid = threadIdx.x, lane = tid & 63, w = tid >> 6;
    int x = blockIdx.x, nt = blockIdx.y;
    int quad = lane >> 4, col = lane & 15;
    int rsel = lane >> 3, seg = lane & 7;   // glds: 8 rows x 8 segs of 16B per call

    const unsigned short* arow = Ap + (size_t)(nt * 128 + w * 32 + col) * 256;
    const unsigned short* Bbase = Bp + (size_t)(x * 128) * 256;

    f32x4 acc[2][8];
    #pragma unroll
    for (int i = 0; i < 2; ++i)
        #pragma unroll
        for (int j = 0; j < 8; ++j) acc[i][j] = (f32x4){0.f, 0.f, 0.f, 0.f};

    // stage B chunk kc into lds_b[bsel]: 16 calls of 1KB (4/wave), r10 swizzle.
    auto stage_chunk = [&](int kc, int bsel) {
        int k0s = kc * 64;
        #pragma unroll
        for (int p = 0; p < 4; ++p) {
            int c = w * 4 + p;
            const unsigned short* gb =
                Bbase + (size_t)(c * 8 + rsel) * 256 + k0s + ((seg ^ (rsel & 7)) * 8);
            __builtin_amdgcn_global_load_lds(
                (const __attribute__((address_space(1))) void*)gb,
                (__attribute__((address_space(3))) void*)(&lds_b[bsel][c * 512]),
                16, 0, 0);
        }
    };

    stage_chunk(0, 0);   // prologue

    #pragma unroll
    for (int kcc = 0; kcc < 4; ++kcc) {
        int k0 = kcc * 64;
        int cur = kcc & 1;
        bf16x8 af[2][2];
        #pragma unroll
        for (int i = 0; i < 2; ++i)
            #pragma unroll
            for (int h = 0; h < 2; ++h)
                af[i][h] = *(const bf16x8*)(arow + i * 16 * 256 + k0 + h * 32 + quad * 8);
        asm volatile("" ::: "memory");   // af above / glds below: fixes issue order
        if (kcc < 3) {
            stage_chunk(kcc + 1, cur ^ 1);
            // newer vmem ops = af(4) + glds_next(4) = 8 (in-order retirement).
            asm volatile("s_waitcnt vmcnt(8)" ::: "memory");
        } else {
            asm volatile("s_waitcnt vmcnt(4)" ::: "memory");
        }
        __builtin_amdgcn_s_barrier();    // all waves' glds for cur buffer done
        asm volatile("" ::: "memory");
        __builtin_amdgcn_s_setprio(1);
        #pragma unroll
        for (int h = 0; h < 2; ++h) {
            bf16x8 bf[8];
            #pragma unroll
            for (int j = 0; j < 8; ++j)
                bf[j] = *(const bf16x8*)(&lds_b[cur][(j * 16 + col) * 64 +
                                         (((h * 4 + quad) ^ (col & 7)) * 8)]);
            #pragma unroll
            for (int i = 0; i < 2; ++i)
                #pragma unroll
                for (int j = 0; j < 8; ++j)
                    acc[i][j] = __builtin_amdgcn_mfma_f32_16x16x32_bf16(
                        af[i][h], bf[j], acc[i][j], 0, 0, 0);
        }
        __builtin_amdgcn_s_setprio(0);
        asm volatile("" ::: "memory");
        if (kcc < 3) {
            __builtin_amdgcn_s_barrier();
            asm volatile("" ::: "memory");
        }
    }

    // epilogue: d' = (wsq[e]+4096) - 2*dot (always positive) -> raw bits are
    // u32-sortable. key = (bits & ~0x7F) | e_local. Branchless top-2, 16-lane
    // merge, write to slice-major s1.
    unsigned m1[2][4], m2[2][4];
    #pragma unroll
    for (int i = 0; i < 2; ++i)
        #pragma unroll
        for (int r = 0; r < 4; ++r) { m1[i][r] = 0xFFFFFFFFu; m2[i][r] = 0xFFFFFFFFu; }
    #pragma unroll
    for (int j = 0; j < 8; ++j) {
        int e = x * 128 + j * 16 + col;
        unsigned jc = (unsigned)(j * 16 + col);   // e_local, 7 bits
        float wq_off = wsq[e] + 4096.0f;
        #pragma unroll
        for (int i = 0; i < 2; ++i)
            #pragma unroll
            for (int r = 0; r < 4; ++r) {
                float d = fmaf(-2.0f, acc[i][j][r], wq_off);
                unsigned k = (__float_as_uint(d) & 0xFFFFFF80u) | jc;
                unsigned mx = (m1[i][r] > k) ? m1[i][r] : k;
                m1[i][r] = (m1[i][r] < k) ? m1[i][r] : k;
                m2[i][r] = (m2[i][r] < mx) ? m2[i][r] : mx;
            }
    }
    #pragma unroll
    for (int i = 0; i < 2; ++i)
        #pragma unroll
        for (int r = 0; r < 4; ++r) {
            unsigned a1 = m1[i][r], a2 = m2[i][r];
            #pragma unroll
            for (int off = 1; off < 16; off <<= 1) {
                unsigned b1 = __shfl_xor(a1, off, 64);
                unsigned b2 = __shfl_xor(a2, off, 64);
                unsigned lo1 = a1 < b1 ? a1 : b1;
                unsigned hi1 = a1 < b1 ? b1 : a1;
                unsigned lo2 = a2 < b2 ? a2 : b2;
                a1 = lo1;
                a2 = hi1 < lo2 ? hi1 : lo2;
            }
            if (col == 0) {
                int q = nt * 128 + w * 32 + i * 16 + quad * 4 + r;
                size_t o = (size_t)x * (NQ * 2) + (size_t)q * 2;   // slice-major
                s1[o] = a1; s1[o + 1] = a2;
            }
        }
}

// ---------- fallback fp32 path (used when ws_size < WS_NEED) ----------
__global__ __launch_bounds__(256, 2) void dist_fp32(const float* __restrict__ z,
                                                    const float* __restrict__ w,
                                                    const float* __restrict__ wsq,
                                                    unsigned long long* __restrict__ best) {
    __shared__ float lds_a[32 * 128];
    __shared__ float lds_b[32 * 132];
    int tid = threadIdx.x;
    int tx = tid & 15, ty = tid >> 4;
    int n0 = blockIdx.y * 128;
    int bb_ = n0 >> 12, lhw0 = n0 & 4095;
    const float* zb = z + (size_t)bb_ * (EDIM * LHW) + lhw0;
    int ebase = blockIdx.x * 2048;
    unsigned long long runmin[8];
    #pragma unroll
    for (int i = 0; i < 8; ++i) runmin[i] = ~0ull;
    float acc[64];
    for (int et = 0; et < 16; ++et) {
        int e0 = ebase + et * 128;
        #pragma unroll
        for (int i = 0; i < 64; ++i) acc[i] = 0.f;
        for (int kc = 0; kc < 8; ++kc) {
            int k0 = kc * 32;
            #pragma unroll
            for (int p = 0; p < 4; ++p) {
                int f = p * 256 + tid;
                int kk = f >> 5, nn4 = f & 31;
                float4 v = *(const float4*)(zb + (size_t)(k0 + kk) * LHW + nn4 * 4);
                *((float4*)(lds_a + kk * 128 + nn4 * 4)) = v;
            }
            #pragma unroll
            for (int p = 0; p < 4; ++p) {
                int f = p * 256 + tid;
                int ee = f >> 3, kk4 = f & 7;
                float4 v = *(const float4*)(w + (size_t)(e0 + ee) * EDIM + k0 + kk4 * 4);
                lds_b[(kk4 * 4 + 0) * 132 + ee] = v.x;
                lds_b[(kk4 * 4 + 1) * 132 + ee] = v.y;
                lds_b[(kk4 * 4 + 2) * 132 + ee] = v.z;
                lds_b[(kk4 * 4 + 3) * 132 + ee] = v.w;
            }
            __syncthreads();
            #pragma unroll
            for (int k = 0; k < 32; ++k) {
                float a[8], bv[8];
                *(float4*)(a)      = *(float4*)(lds_a + k * 128 + ty * 8);
                *(float4*)(a + 4)  = *(float4*)(lds_a + k * 128 + ty * 8 + 4);
                *(float4*)(bv)     = *(float4*)(lds_b + k * 132 + tx * 8);
                *(float4*)(bv + 4) = *(float4*)(lds_b + k * 132 + tx * 8 + 4);
                #pragma unroll
                for (int i = 0; i < 8; ++i)
                    #pragma unroll
                    for (int j = 0; j < 8; ++j)
                        acc[i * 8 + j] = fmaf(a[i], bv[j], acc[i * 8 + j]);
            }
            __syncthreads();
        }
        #pragma unroll
        for (int i = 0; i < 8; ++i) {
            unsigned long long m = runmin[i];
            #pragma unroll
            for (int j = 0; j < 8; ++j) {
                int e = e0 + tx * 8 + j;
                float d = wsq[e] - 2.0f * acc[i * 8 + j];
                unsigned long long key =
                    ((unsigned long long)f32_sortable(d) << 32) | (unsigned)e;
                m = (m < key) ? m : key;
            }
            runmin[i] = m;
        }
    }
    #pragma unroll
    for (int i = 0; i < 8; ++i) {
        unsigned long long kk = runmin[i];
        #pragma unroll
        for (int off = 8; off >= 1; off >>= 1) {
            unsigned long long o = __shfl_xor(kk, off, 16);
            kk = (kk < o) ? kk : o;
        }
        if (tx == 0) atomicMin(&best[n0 + ty * 8 + i], kk);
    }
}

__global__ __launch_bounds__(256) void extract_idx(const unsigned long long* __restrict__ best,
                                                   unsigned* __restrict__ idxarr) {
    int n = blockIdx.x * 256 + threadIdx.x;
    idxarr[n] = (unsigned)(best[n] & 0xFFFFFFFFull) & (NE - 1);
}

// K3 v17: refine + gather + finalize fused. One 1024-thread block per 64 q.
//  A: stage the block's whole z tile (64 lhw x 256 d, 68 KB) into LDS once.
//  B: refine per wave (4 q each): slice-major s1 column read, 3-step 8-lane
//     top-2 merge, 16 exact fp32 candidates (z from LDS, w float4), argmin.
//     (s1 == nullptr -> fallback path: read idxarr instead.)
//  C: load selected w rows to LDS.  D: out/loss from LDS z (no global z
//  re-read).  E: last-block finalize.  LDS ~136 KB -> 1 block/CU (as before).
__global__ __launch_bounds__(1024) void gather_kernel(const float* __restrict__ z,
                                                      const float* __restrict__ w,
                                                      const float* __restrict__ wsq,
                                                      const unsigned* __restrict__ s1,
                                                      const unsigned* __restrict__ idxarr,
                                                      unsigned* __restrict__ counts,
                                                      float* __restrict__ loss,
                                                      unsigned* __restrict__ done,
                                                      float* __restrict__ out,
                                                      float* __restrict__ out_idx,
                                                      float* __restrict__ out_scalars) {
    __shared__ float zt[64 * 272];       // [lhw][d], pad 272 (16B-aligned rows, 2-way banks)
    __shared__ float wl[64 * 257];
    __shared__ int idx_s[64];
    __shared__ float lsum[16];
    __shared__ int usum[16];
    __shared__ unsigned lastflag;
    int tid = threadIdx.x, lane = tid & 63, wv = tid >> 6;
    int n0 = blockIdx.x * 64;
    int bb_ = n0 >> 12, lhw0 = n0 & 4095;    // block never crosses a b boundary
    const float* zb = z + (size_t)bb_ * (EDIM * LHW) + lhw0;

    // ---- A: z tile -> LDS (coalesced: 64 consecutive lhw per d) ----
    {
        int l = tid & 63, dg = tid >> 6;     // dg in [0,16)
        #pragma unroll
        for (int i = 0; i < 16; ++i) {
            int d = dg * 16 + i;
            zt[l * 272 + d] = zb[(size_t)d * LHW + l];
        }
    }
    __syncthreads();

    // ---- B: refine (4 q per wave) ----
    if (s1 != nullptr) {
        #pragma unroll
        for (int jq = 0; jq < 4; ++jq) {
            int ql = wv * 4 + jq;            // local q (== local lhw)
            int q = n0 + ql;
            uint2 kk2 = *(const uint2*)(s1 + ((size_t)lane * NQ + q) * 2);
            unsigned long long a1 = ((unsigned long long)(kk2.x >> 7) << 13)
                                  | (unsigned)(lane * 128 + (kk2.x & 127u));
            unsigned long long a2 = ((unsigned long long)(kk2.y >> 7) << 13)
                                  | (unsigned)(lane * 128 + (kk2.y & 127u));
            #pragma unroll
            for (int off = 1; off < 8; off <<= 1) {
                unsigned long long b1 = __shfl_xor(a1, off, 64);
                unsigned long long b2 = __shfl_xor(a2, off, 64);
                unsigned long long lo1 = a1 < b1 ? a1 : b1;
                unsigned long long hi1 = a1 < b1 ? b1 : a1;
                unsigned long long lo2 = a2 < b2 ? a2 : b2;
                a1 = lo1;
                a2 = hi1 < lo2 ? hi1 : lo2;
            }
            float4 zv4 = *(const float4*)(&zt[ql * 272 + lane * 4]);
            unsigned long long bestk = ~0ull;
            #pragma unroll
            for (int c = 0; c < 16; ++c) {
                int src = (c >> 1) * 8;
                unsigned long long kc = (c & 1) ? __shfl(a2, src, 64)
                                                : __shfl(a1, src, 64);
                unsigned e = (unsigned)(kc & (unsigned long long)(NE - 1));
                float4 wv4 = *(const float4*)(w + (size_t)e * EDIM + lane * 4);
                float p = zv4.x * wv4.x + zv4.y * wv4.y +
                          zv4.z * wv4.z + zv4.w * wv4.w;
                #pragma unroll
                for (int off = 32; off; off >>= 1) p += __shfl_xor(p, off, 64);
                float d = wsq[e] - 2.0f * p;
                unsigned long long key =
                    ((unsigned long long)f32_sortable(d) << 32) | e;
                if (key < bestk) bestk = key;
            }
            if (lane == 0) {
                int idx = (int)(bestk & 0xFFFFFFFFull) & (NE - 1);
                idx_s[ql] = idx;
                out_idx[q] = (float)idx;
                atomicAdd(&counts[idx], 1u);
            }
        }
    } else {
        // fallback: indices precomputed by extract_idx
        if (tid < 64) {
            int idx = (int)(idxarr[n0 + tid] & (NE - 1));
            idx_s[tid] = idx;
            out_idx[n0 + tid] = (float)idx;
            atomicAdd(&counts[idx], 1u);
        }
    }
    __syncthreads();

    // ---- C: gather selected codebook rows to LDS ----
    {
        int r0 = tid >> 8, cl = tid & 255;   // 4 row-groups x 256 cols
        #pragma unroll
        for (int i = 0; i < 16; ++i)
            wl[(r0 + i * 4) * 257 + cl] = w[(size_t)idx_s[r0 + i * 4] * EDIM + cl];
    }
    __syncthreads();

    // ---- D: out/loss from LDS z + LDS w ----
    int tn = tid & 63, tc = tid >> 6;        // tc in [0,16): 16 d-groups of 16
    size_t ob = (size_t)bb_ * (EDIM * LHW) + lhw0 + tn;
    float accl = 0.f;
    #pragma unroll
    for (int cc = 0; cc < 16; ++cc) {
        int c = tc * 16 + cc;
        float wv_ = wl[tn * 257 + c];
        float zv = zt[tn * 272 + c];
        float diff = wv_ - zv;               // z_q - zc
        out[ob + (size_t)c * LHW] = zv + diff;
        accl += diff * diff;
    }
    #pragma unroll
    for (int off = 32; off; off >>= 1) accl += __shfl_xor(accl, off, 64);
    if (lane == 0) lsum[wv] = accl;
    __syncthreads();
    if (tid < 16) {
        float v = lsum[tid];
        v += __shfl_xor(v, 8, 16);
        v += __shfl_xor(v, 4, 16);
        v += __shfl_xor(v, 2, 16);
        v += __shfl_xor(v, 1, 16);
        if (tid == 0) atomicAdd(loss, v);
    }

    // ---- E: last-block finalize ----
    __syncthreads();
    if (tid == 0) {
        __threadfence();                     // release
        lastflag = (atomicAdd(done, 1u) == (unsigned)(NQ / 64 - 1));
    }
    __syncthreads();
    if (lastflag) {
        __threadfence();                     // acquire
        float s = 0.f;
        int uniq = 0;
        for (int i = tid; i < NE; i += 1024) {
            unsigned c = counts[i];
            if (c > 0) {
                float p = (float)c * (1.0f / (float)NQ);
                s += p * logf(p + 1e-10f);
                uniq++;
            }
        }
        #pragma unroll
        for (int off = 32; off; off >>= 1) {
            s += __shfl_xor(s, off, 64);
            uniq += __shfl_xor(uniq, off, 64);
        }
        if (lane == 0) { lsum[wv] = s; usum[wv] = uniq; }
        __syncthreads();
        if (tid == 0) {
            float st = 0.f;
            int ut = 0;
            #pragma unroll
            for (int i = 0; i < 16; ++i) { st += lsum[i]; ut += usum[i]; }
            out_scalars[0] = BETA * loss[0] * (1.0f / (float)(NQ * EDIM));  // loss
            out_scalars[1] = expf(-st);                                     // perplexity
            out_scalars[2] = (float)ut;                                     // unique
        }
    }
}

extern "C" void kernel_launch(void* const* d_in, const int* in_sizes, int n_in,
                              void* d_out, int out_size, void* d_ws, size_t ws_size,
                              hipStream_t stream) {
    const float* z = (const float*)d_in[0];
    const float* w = (const float*)d_in[1];
    float* out = (float*)d_out;
    char* ws = (char*)d_ws;
    float* wsq = (float*)(ws + WS_WSQ);
    unsigned* counts = (unsigned*)(ws + WS_CNT);
    float* loss = (float*)(ws + WS_LOSS);
    unsigned* done = (unsigned*)(ws + WS_LOSS + 4);
    unsigned* idxarr = (unsigned*)(ws + WS_IDX);
    unsigned long long* best = (unsigned long long*)(ws + WS_BEST);
    unsigned* Ap = (unsigned*)(ws + WS_APACK);
    unsigned* Bp = (unsigned*)(ws + WS_BPACK);
    unsigned* s1 = (unsigned*)(ws + WS_S1);

    int idx_off = out_size - NQ;
    int scal_off = idx_off - 3;
    float* out_idx = out + idx_off;
    float* out_scalars = out + scal_off;

    if (ws_size >= (size_t)WS_NEED) {
        pack_all<<<768, 1024, 0, stream>>>(w, z, wsq, Bp, Ap, counts, loss, done);
        dist_mfma<<<dim3(64, 128), 256, 0, stream>>>((const unsigned short*)Ap,
                                                     (const unsigned short*)Bp, wsq, s1);
        gather_kernel<<<NQ / 64, 1024, 0, stream>>>(z, w, wsq, s1, idxarr, counts,
                                                    loss, done, out, out_idx, out_scalars);
    } else {
        hipMemsetAsync(counts, 0, NE * sizeof(unsigned), stream);
        hipMemsetAsync(loss, 0, 8, stream);   // loss + done
        wsq_kernel<<<NE / 4, 256, 0, stream>>>(w, wsq);
        hipMemsetAsync(best, 0xFF, NQ * sizeof(unsigned long long), stream);
        dist_fp32<<<dim3(4, 128), 256, 0, stream>>>(z, w, wsq, best);
        extract_idx<<<NQ / 256, 256, 0, stream>>>(best, idxarr);
        gather_kernel<<<NQ / 64, 1024, 0, stream>>>(z, w, wsq, nullptr, idxarr, counts,
                                                    loss, done, out, out_idx, out_scalars);
    }
}